// Round 7
// baseline (1072.658 us; speedup 1.0000x reference)
//
#include <hip/hip_runtime.h>

// Decoder GRU, B=128 T=512 X=64 H=256, skip runtime (skip==0 -> generic
// path).  Round 13: R12 + stall surgery.
//
// R12 landed full weight residency (FETCH 2.5 MB one-time; 128 arch VGPR +
// 128 AGPR = full 256/wave budget; whh_rz in AGPRs).  4950 cyc/step vs
// ~1500 floor = stall-bound.  Three fixes, no structural change:
//  1. Remove MSTEP's sched_barrier(0)s and put PROJ FIRST: PROJ reads
//     pt2[p] from step i-1 -> independent of GATES(i); its 16 reg-dots +
//     4 LDS reads now fill the post-barrier h4/wn4 load-latency window.
//  2. hid2 kh=1 half padded +4 words (word 68): kills the 2-way bank
//     conflict on every h4 broadcast read (R10/R12's constant 2^25
//     SQ_LDS_BANK_CONFLICT = 512 cyc/WG/step).
//  3. xor1/xor2 shuffles -> DPP quad_perm (VALU, no DS pipe, no lgkm wait):
//     4 reduces in GATES, 2 in PROJ, 2 moves in the update tail.
// Weights: whh_rz 32 u4 (AGPR) + wih 12 u4 + wout 4 u4 (arch) resident;
// W_hh n-gate 128 KB in LDS [u][t].  1 barrier/step (R7/R12 verified math).
typedef _Float16 h2_t __attribute__((ext_vector_type(2)));

constexpr int T_ = 512;
constexpr int X_ = 64;
constexpr int H_ = 256;
constexpr int NWG = 128;  // 1 batch per WG, 1 WG/CU
constexpr int NT = 512;   // 8 waves = 2/EU
constexpr int RS = 16;    // ring slots; lookback 2*skip, OK for skip <= 7

// fp16 weight image in d_ws (uint4 units), all [u][t] with t = threadIdx:
//   u  0..31 : W_hh gates r,z   (g=u>>4, j=u&15; c=t>>1, kh=t&1)
//   u 32..47 : W_hh gate n      (j=u-32)
//   u 48..59 : W_ih 3 gates     (g=(u-48)>>2, j=(u-48)&3)
//   u 60..63 : W_out            (j=u-60; xc=t>>3, sl=t&7)
constexpr int G_TOTAL = 64 * NT;  // 32768 uint4 = 512 KB

__device__ __forceinline__ float sigmoid_f(float x) {
  float e = __expf(fminf(-x, 80.f));
  return 1.f / (1.f + e);
}
__device__ __forceinline__ float tanh_f(float x) {
  float e = __expf(fminf(-2.f * x, 80.f));
  return (1.f - e) / (1.f + e);
}

__device__ __forceinline__ unsigned pk2(float a, float b) {
  h2_t v;
  v[0] = (_Float16)a;
  v[1] = (_Float16)b;
  return __builtin_bit_cast(unsigned, v);
}
__device__ __forceinline__ uint4 pk8(const float* s) {
  return make_uint4(pk2(s[0], s[1]), pk2(s[2], s[3]), pk2(s[4], s[5]),
                    pk2(s[6], s[7]));
}

// fp16-pair dot with fp32 accumulate (v_dot2_f32_f16)
__device__ __forceinline__ float dotp(unsigned w, unsigned h, float acc) {
  h2_t wv = __builtin_bit_cast(h2_t, w);
  h2_t hv = __builtin_bit_cast(h2_t, h);
#if __has_builtin(__builtin_amdgcn_fdot2)
  return __builtin_amdgcn_fdot2(wv, hv, acc, false);
#else
  acc = fmaf((float)wv[0], (float)hv[0], acc);
  return fmaf((float)wv[1], (float)hv[1], acc);
#endif
}
__device__ __forceinline__ float dotq(uint4 w, uint4 h, float acc) {
  acc = dotp(w.x, h.x, acc);
  acc = dotp(w.y, h.y, acc);
  acc = dotp(w.z, h.z, acc);
  acc = dotp(w.w, h.w, acc);
  return acc;
}

// DPP quad_perm helpers: xor1 = [1,0,3,2] = 0xB1, xor2 = [2,3,0,1] = 0x4E.
// VALU-only lane exchange (no DS pipe, no lgkmcnt wait).
__device__ __forceinline__ float dpp_xor1(float x) {
  int v = __builtin_amdgcn_update_dpp(0, __builtin_bit_cast(int, x), 0xB1,
                                      0xF, 0xF, true);
  return __builtin_bit_cast(float, v);
}
__device__ __forceinline__ float dpp_xor2(float x) {
  int v = __builtin_amdgcn_update_dpp(0, __builtin_bit_cast(int, x), 0x4E,
                                      0xF, 0xF, true);
  return __builtin_bit_cast(float, v);
}

// One-time fp32 -> fp16 pack + transpose into register/LDS-friendly layouts.
__global__ void prep_kernel(const float* __restrict__ Wih,
                            const float* __restrict__ Whh,
                            const float* __restrict__ Wout,
                            uint4* __restrict__ G) {
  int id = blockIdx.x * 256 + threadIdx.x;
  if (id >= G_TOTAL) return;
  int t = id & (NT - 1), u = id >> 9;
  int c = t >> 1, kh = t & 1;
  if (u < 32) {  // W_hh r,z
    int g = u >> 4, j = u & 15;
    G[id] = pk8(Whh + (size_t)(g * 256 + c) * H_ + kh * 128 + j * 8);
  } else if (u < 48) {  // W_hh n
    int j = u - 32;
    G[id] = pk8(Whh + (size_t)(512 + c) * H_ + kh * 128 + j * 8);
  } else if (u < 60) {  // W_ih
    int v = u - 48, g = v >> 2, j = v & 3;
    G[id] = pk8(Wih + (size_t)(g * 256 + c) * X_ + kh * 32 + j * 8);
  } else {  // W_out
    int j = u - 60, xc = t >> 3, sl = t & 7;
    G[id] = pk8(Wout + (size_t)xc * H_ + sl * 32 + j * 8);
  }
}

// padded pt2 word index: block (cp>>4) stride 36 words -> PROJ's 8
// sl-address-groups start at disjoint bank quads.
#define PTW(cp) (((cp) >> 4) * 36 + ((cp)&15))
// padded hid2 word index: kh=1 half starts at word 68 (banks 4-7, disjoint
// from kh=0's banks 0-3) -> h4 broadcast reads conflict-free.
#define HIW(w) ((w) + (((w) >> 6) << 2))

// ---- per-step building blocks (p/q compile-time 0/1 in the main loop) ----

#define GATES(p, i, hn)                                                      \
  float hn;                                                                  \
  {                                                                          \
    float a0 = 0, a1 = 0, z0 = 0, z1 = 0, n0 = 0, n1 = 0, ni = 0;            \
    const uint4* h4 = ((const uint4*)hid2[p]) + kh * 17;                     \
    _Pragma("unroll") for (int j = 0; j < 16; j += 2) {                      \
      uint4 ha = h4[j], hb = h4[j + 1]; /* broadcast, disjoint banks */      \
      uint4 wna = wn4[j * NT + t], wnb = wn4[(j + 1) * NT + t];              \
      a0 = dotq(whh_rz[j], ha, a0);                                          \
      a1 = dotq(whh_rz[j + 1], hb, a1);                                      \
      z0 = dotq(whh_rz[16 + j], ha, z0);                                     \
      z1 = dotq(whh_rz[17 + j], hb, z1);                                     \
      n0 = dotq(wna, ha, n0);                                                \
      n1 = dotq(wnb, hb, n1);                                                \
    }                                                                        \
    const uint4* x4 = ((const uint4*)xt2[p]) + kh * 4;                       \
    _Pragma("unroll") for (int j = 0; j < 4; ++j) {                          \
      uint4 xa = x4[j];                                                      \
      a0 = dotq(wih[j], xa, a0);                                             \
      z0 = dotq(wih[4 + j], xa, z0);                                         \
      ni = dotq(wih[8 + j], xa, ni);                                         \
    }                                                                        \
    float ar = a0 + a1, az = z0 + z1, anh = n0 + n1;                         \
    ar += dpp_xor1(ar);                                                      \
    az += dpp_xor1(az);                                                      \
    anh += dpp_xor1(anh);                                                    \
    ni += dpp_xor1(ni);                                                      \
    float r = sigmoid_f(ar + bsr);                                           \
    float z = sigmoid_f(az + bsz);                                           \
    float n = tanh_f(ni + bin_ + r * (anh + bhn_));                          \
    hn = fmaf(z, hid_reg - n, n); /* (1-z)*n + z*hidden */                   \
    if (kh == 0) ring[(i) & (RS - 1)][c] = hn;                               \
  }

#define PROJ_FIN(q, i)                                                       \
  {                                                                          \
    fa += dpp_xor1(fa);                                                      \
    fa += dpp_xor2(fa);                                                      \
    fa += __shfl_xor(fa, 4);                                                 \
    float o = fa + bo;                                                       \
    if (sl == 0) out[ob + (size_t)(i)*X_ + xc] = o;                          \
    float oo = __shfl_xor(o, 8);                                             \
    if ((t & 15) == 0) xt2[q][t >> 4] = pk2(o, oo);                          \
  }

#define PROJ(p, q, i)                                                        \
  {                                                                          \
    float fa = 0;                                                            \
    const uint4* p4 = (const uint4*)&pt2[p][sl * 36];                        \
    _Pragma("unroll") for (int j = 0; j < 4; ++j) fa =                       \
        dotq(wout[j], p4[j], fa);                                            \
    PROJ_FIN(q, i)                                                           \
  }

// Main-loop step (valid for i >= 2*skip, skip >= 1): pt2[p] was produced at
// step i-1 -> PROJ is independent of GATES(i); its dots are issued FIRST so
// the scheduler can fill GATES' LDS-load latency with them.
#define MSTEP(i, p, q)                                                       \
  {                                                                          \
    float fa = 0;                                                            \
    const uint4* p4 = (const uint4*)&pt2[p][sl * 36];                        \
    _Pragma("unroll") for (int j = 0; j < 4; ++j) fa =                       \
        dotq(wout[j], p4[j], fa);                                            \
    GATES(p, i, hn)                                                          \
    PROJ_FIN(q, i)                                                           \
    if ((i) + 1 < T_) {                                                      \
      float sgp = ring[((i) + 1 - 2 * skip) & (RS - 1)][c];                  \
      float hidn = m0f[(i) + 1] * hn + m1f[(i) + 1] * sgp;                   \
      float ptn = hn + sgp;                                                  \
      hid_reg = hidn;                                                        \
      float ho = dpp_xor2(hidn);                                             \
      float po = dpp_xor2(ptn);                                              \
      if ((t & 3) == 0) {                                                    \
        int w = t >> 2;                                                      \
        hid2[q][HIW(w)] = pk2(hidn, ho);                                     \
        pt2[q][PTW(w)] = pk2(ptn, po);                                       \
      }                                                                      \
    }                                                                        \
    __syncthreads();                                                         \
  }

__global__ __attribute__((amdgpu_flat_work_group_size(NT, NT),
                          amdgpu_waves_per_eu(2, 2))) void decoder_kernel(
    const float* __restrict__ h_enc, const float* __restrict__ b_ih,
    const float* __restrict__ b_hh, const float* __restrict__ b_out,
    const int* __restrict__ mask0, const int* __restrict__ mask1,
    const int* __restrict__ skipp, const uint4* __restrict__ G,
    float* __restrict__ out) {
  __shared__ alignas(16) uint4 wn4[16 * NT];       // 128 KB W_hh n-gate [u][t]
  __shared__ float ring[RS][H_];                   // 16 KB h history (fp32)
  __shared__ alignas(16) unsigned hid2[2][136];    // fp16 hidden, kh-padded
  __shared__ alignas(16) unsigned pt2[2][8 * 36];  // fp16 h_prev+skip, padded
  __shared__ alignas(16) unsigned xt2[2][X_ / 2];  // fp16 x feedback pairs
  __shared__ float m0f[T_], m1f[T_];               // 4 KB masks
  // total ~= 131072+16384+1088+2304+256+4096 = 155200 B (151.6 KB)

  const int t = threadIdx.x;
  const int b = blockIdx.x;
  const int c = t >> 1, kh = t & 1;   // gate role: column, k-half
  const int xc = t >> 3, sl = t & 7;  // projection role
  const size_t ob = (size_t)b * T_ * X_;

  // ---- resident weight registers: 48 uint4 = 192 regs/thread ----
  uint4 whh_rz[32];  // r,z gates, 128 k each (lands in AGPRs)
  uint4 wih[12];     // 3 gates x 32 k
  uint4 wout[4];     // 32 k-slice of own xc column
#pragma unroll
  for (int u = 0; u < 32; ++u) whh_rz[u] = G[u * NT + t];
#pragma unroll
  for (int u = 0; u < 12; ++u) wih[u] = G[(48 + u) * NT + t];
#pragma unroll
  for (int u = 0; u < 4; ++u) wout[u] = G[(60 + u) * NT + t];

  // ---- LDS: n-gate weights + masks ----
#pragma unroll
  for (int u = 0; u < 16; ++u) wn4[u * NT + t] = G[(32 + u) * NT + t];
  m0f[t] = (float)mask0[t];
  m1f[t] = (float)mask1[t];

  const int skip = skipp[0];
  const int i0 = (skip == 0) ? T_ : ((2 * skip < T_) ? 2 * skip : T_);

  const float bsr = b_ih[c] + b_hh[c];
  const float bsz = b_ih[H_ + c] + b_hh[H_ + c];
  const float bin_ = b_ih[2 * H_ + c];
  const float bhn_ = b_hh[2 * H_ + c];
  const float bo = b_out[xc];

  float hp = h_enc[(size_t)b * H_ + c];
  float hid_reg = (float)mask0[0] * hp;  // hidden(0); skip_g(0) == 0
  float hps_reg = hp;                    // h_prev(0) = h_enc
  {
    float ho = dpp_xor2(hid_reg);
    if ((t & 3) == 0) hid2[0][HIW(t >> 2)] = pk2(hid_reg, ho);
  }
  if (t < X_ / 2) xt2[0][t] = 0u;  // GO token
  __syncthreads();

  // ---- prologue: generic 2-barrier steps for i < 2*skip ----
  for (int i = 0; i < i0; ++i) {
    const int p = i & 1, q = p ^ 1;
    GATES(p, i, hn)
    {
      int ppos = (i < skip) ? 2 * i + 1 : i - skip;
      bool pz = ppos < skip;
      int pi = ppos - skip;
      if (pi < 0) pi = 0;
      float sp = pz ? 0.f : ((pi == i) ? hn : ring[pi & (RS - 1)][c]);
      float ptv = hps_reg + sp;
      float po = dpp_xor2(ptv);
      if ((t & 3) == 0) pt2[p][PTW(t >> 2)] = pk2(ptv, po);
    }
    if (i + 1 < T_) {
      int i1 = i + 1;
      int pg = (i1 < skip) ? 2 * i1 : i1 - skip;
      bool gz = pg < skip;
      int gi = pg - skip;
      if (gi < 0) gi = 0;
      if (gi >= i1) gz = true;  // unwritten slot == reference zero init
      float sg = gz ? 0.f : ((gi == i) ? hn : ring[gi & (RS - 1)][c]);
      float hidn = m0f[i1] * hn + m1f[i1] * sg;
      hid_reg = hidn;
      float ho = dpp_xor2(hidn);
      if ((t & 3) == 0) hid2[q][HIW(t >> 2)] = pk2(hidn, ho);
      if (skip > 0 && i1 >= 2 * skip) {  // handoff into fused main loop
        float sgp = ring[(i1 - 2 * skip) & (RS - 1)][c];
        float ptn = hn + sgp;
        float po2 = dpp_xor2(ptn);
        if ((t & 3) == 0) pt2[q][PTW(t >> 2)] = pk2(ptn, po2);
      }
    }
    hps_reg = hn;
    __syncthreads();
    PROJ(p, q, i)
    __syncthreads();
  }

  // ---- main loop: one barrier per step; i0 even so parity is static ----
#pragma unroll 1
  for (int i = i0; i < T_; i += 2) {
    MSTEP(i, 0, 1)
    MSTEP(i + 1, 1, 0)
  }
}

extern "C" void kernel_launch(void* const* d_in, const int* in_sizes, int n_in,
                              void* d_out, int out_size, void* d_ws,
                              size_t ws_size, hipStream_t stream) {
  (void)in_sizes; (void)n_in; (void)out_size; (void)ws_size;
  // d_in[0] = input [B,T,X] — unused by the reference computation.
  const float* h_enc = (const float*)d_in[1];
  const float* W_ih = (const float*)d_in[2];
  const float* W_hh = (const float*)d_in[3];
  const float* b_ih = (const float*)d_in[4];
  const float* b_hh = (const float*)d_in[5];
  const float* W_out = (const float*)d_in[6];
  const float* b_out = (const float*)d_in[7];
  const int* mask0 = (const int*)d_in[8];
  const int* mask1 = (const int*)d_in[9];
  const int* skipp = (const int*)d_in[10];
  float* out = (float*)d_out;
  uint4* G = (uint4*)d_ws;  // 512 KB fp16 weight image

  prep_kernel<<<dim3(G_TOTAL / 256), dim3(256), 0, stream>>>(W_ih, W_hh,
                                                             W_out, G);
  decoder_kernel<<<dim3(NWG), dim3(NT), 0, stream>>>(
      h_enc, b_ih, b_hh, b_out, mask0, mask1, skipp, G, out);
}